// Round 1
// baseline (3863.700 us; speedup 1.0000x reference)
//
#include <hip/hip_runtime.h>
#include <math.h>

// ---------------- workspace layout (bytes, all 256-aligned) ----------------
static constexpr size_t OFF_W1T    = 0;          // 1728 floats   [khw*3+ci][64co]
static constexpr size_t OFF_W2T    = 6912;       // 73728 floats  [khw*64+ci][128co]
static constexpr size_t OFF_W3T    = 301824;     // 294912 floats [khw*128+ci][256co]
static constexpr size_t OFF_CODEST = 1481472;    // 262144 floats [ci][1024k]
static constexpr size_t OFF_CNORM  = 2530048;    // 1024 floats
static constexpr size_t OFF_FC1T   = 2534144;    // 2097152 floats [k][512o]
static constexpr size_t OFF_COUNTS = 10922752;   // 1024 ints
static constexpr size_t OFF_LOSS   = 10926848;   // 1 float
static constexpr size_t OFF_ENC    = 10927104;   // 65536 ints
static constexpr size_t OFF_Y2     = 11189248;   // 33554432 floats; later aliased as q_fea (16777216 floats)
static constexpr size_t OFF_FLAT   = 145406976;  // 16777216 floats; later aliased as h (2097152 floats)
// total: 212515840 bytes (~212.5 MB)

// ---------------- prep: transposes + code norms + zeroing ----------------
__global__ __launch_bounds__(256) void prep_kernel(
    const float* __restrict__ w1, const float* __restrict__ w2,
    const float* __restrict__ w3, const float* __restrict__ code0,
    const float* __restrict__ code1, const float* __restrict__ fc1w,
    const int* __restrict__ idxp,
    float* __restrict__ w1t, float* __restrict__ w2t, float* __restrict__ w3t,
    float* __restrict__ codesT, float* __restrict__ cnorm,
    float* __restrict__ fc1t, int* __restrict__ counts,
    float* __restrict__ loss_sum)
{
    int i = blockIdx.x * 256 + threadIdx.x;
    const int Kc = (idxp[0] == 0) ? 512 : 1024;
    if (i < 1728) {                       // w1t[(khw*3+ci)*64+co] = w1[co][ci][kh][kw]
        int co = i & 63; int rest = i >> 6;      // rest = khw*3+ci
        int ci = rest % 3; int khw = rest / 3;
        w1t[i] = w1[(co * 3 + ci) * 9 + khw];
        return;
    }
    i -= 1728;
    if (i < 73728) {                      // w2t[(khw*64+ci)*128+co]
        int co = i & 127; int rest = i >> 7;
        int ci = rest & 63; int khw = rest >> 6;
        w2t[i] = w2[(co * 64 + ci) * 9 + khw];
        return;
    }
    i -= 73728;
    if (i < 294912) {                     // w3t[(khw*128+ci)*256+co]
        int co = i & 255; int rest = i >> 8;
        int ci = rest & 127; int khw = rest >> 7;
        w3t[i] = w3[(co * 128 + ci) * 9 + khw];
        return;
    }
    i -= 294912;
    if (i < 262144) {                     // codesT[ci*1024+k]
        int k = i & 1023; int ci = i >> 10;
        if (k < Kc)
            codesT[i] = (k < 512) ? code0[k * 256 + ci] : code1[(k - 512) * 256 + ci];
        return;
    }
    i -= 262144;
    if (i < 2097152) {                    // fc1t[k*512+o] = fc1w[o*4096+k]
        int o = i & 511; int k = i >> 9;
        fc1t[i] = fc1w[(size_t)o * 4096 + k];
        return;
    }
    i -= 2097152;
    if (i < 1024) {                       // cnorm[k] = ||code_k||^2
        if (i < Kc) {
            const float* c = (i < 512) ? code0 + (size_t)i * 256
                                       : code1 + (size_t)(i - 512) * 256;
            float s = 0.f;
            for (int ci = 0; ci < 256; ++ci) s += c[ci] * c[ci];
            cnorm[i] = s;
        } else {
            cnorm[i] = 0.f;
        }
        return;
    }
    i -= 1024;
    if (i < 1024) { counts[i] = 0; return; }
    i -= 1024;
    if (i == 0) loss_sum[0] = 0.f;
}

// ---------------- fused conv1+conv2 (half image per block) ----------------
// conv1: [3,32,32] -> relu -> y1 [16,16,64] (LDS, padded, 9-row half)
// conv2: y1 -> relu -> y2 NHWC [8,8,128] (this block writes its 4 oh rows)
__global__ __launch_bounds__(256) void conv12_kernel(
    const float* __restrict__ x, const float* __restrict__ w1t,
    const float* __restrict__ b1, const float* __restrict__ w2t,
    const float* __restrict__ b2, float* __restrict__ y2)
{
    __shared__ float xsp[3][34][34];     // padded input image, 13.9 KB
    __shared__ float y1p[9][18][64];     // padded conv1 half, 41.5 KB
    const int t = threadIdx.x;
    const int n = blockIdx.x >> 1;
    const int h = blockIdx.x & 1;        // which half (oh 0..3 / 4..7 of conv2)

    for (int i = t; i < 3 * 34 * 34; i += 256) ((float*)xsp)[i] = 0.0f;
    for (int i = t; i < 9 * 18 * 64; i += 256) ((float*)y1p)[i] = 0.0f;
    __syncthreads();
    const float* xn = x + (size_t)n * 3072;
    for (int i = t; i < 768; i += 256) {
        float4 v = ((const float4*)xn)[i];
        int ci = i >> 8, rem = i & 255;
        int ih = rem >> 3, iw = (rem & 7) << 2;
        float* d = &xsp[ci][ih + 1][iw + 1];
        d[0] = v.x; d[1] = v.y; d[2] = v.z; d[3] = v.w;
    }
    __syncthreads();

    // ---- conv1: rows oh1 = 8h-1 .. 8h+7 (9 rows, OOB row stays zero) ----
    {
        const int co = t & 63;
        const int wv = t >> 6;           // wave id 0..3
        float wr[27];
        #pragma unroll
        for (int kk = 0; kk < 27; ++kk) wr[kk] = w1t[kk * 64 + co];
        const float bias = b1[co];
        for (int i = 0; i < 36; ++i) {
            int p = wv + 4 * i;          // 0..143 (9 rows x 16 cols)
            int l = p >> 4, ow = p & 15;
            int oh = 8 * h - 1 + l;
            if (oh >= 0 && oh < 16) {
                float acc = bias;
                #pragma unroll
                for (int kh = 0; kh < 3; ++kh)
                    #pragma unroll
                    for (int kw = 0; kw < 3; ++kw)
                        #pragma unroll
                        for (int ci = 0; ci < 3; ++ci)
                            acc += xsp[ci][2 * oh + kh][2 * ow + kw] *
                                   wr[(kh * 3 + kw) * 3 + ci];
                y1p[l][ow + 1][co] = fmaxf(acc, 0.0f);
            }
        }
    }
    __syncthreads();

    // ---- conv2: 4co x 4pix register tile per thread ----
    {
        const int co4 = t & 31;          // co = co4*4
        const int pg  = t >> 5;          // 0..7, pixels pg*4..pg*4+3 of 32
        float4 acc[4];
        float4 bias = ((const float4*)b2)[co4];
        #pragma unroll
        for (int j = 0; j < 4; ++j) acc[j] = bias;
        #pragma unroll
        for (int kh = 0; kh < 3; ++kh)
        #pragma unroll
        for (int kw = 0; kw < 3; ++kw) {
            #pragma unroll 4
            for (int c4 = 0; c4 < 16; ++c4) {
                const float4* wp = (const float4*)w2t + ((kh * 3 + kw) * 64 + c4 * 4) * 32;
                float4 w0 = wp[co4];
                float4 w1v = wp[32 + co4];
                float4 w2v = wp[64 + co4];
                float4 w3v = wp[96 + co4];
                #pragma unroll
                for (int j = 0; j < 4; ++j) {
                    int p = pg * 4 + j;
                    int ohh = p >> 3, ow = p & 7;
                    float4 f = *(const float4*)&y1p[2 * ohh + kh][2 * ow + kw][c4 * 4];
                    acc[j].x += f.x * w0.x + f.y * w1v.x + f.z * w2v.x + f.w * w3v.x;
                    acc[j].y += f.x * w0.y + f.y * w1v.y + f.z * w2v.y + f.w * w3v.y;
                    acc[j].z += f.x * w0.z + f.y * w1v.z + f.z * w2v.z + f.w * w3v.z;
                    acc[j].w += f.x * w0.w + f.y * w1v.w + f.z * w2v.w + f.w * w3v.w;
                }
            }
        }
        #pragma unroll
        for (int j = 0; j < 4; ++j) {
            int p = pg * 4 + j;
            int ohh = p >> 3, ow = p & 7;
            float4 v = acc[j];
            v.x = fmaxf(v.x, 0.f); v.y = fmaxf(v.y, 0.f);
            v.z = fmaxf(v.z, 0.f); v.w = fmaxf(v.w, 0.f);
            ((float4*)(y2 + ((size_t)n * 64 + (h * 4 + ohh) * 8 + ow) * 128))[co4] = v;
        }
    }
}

// ---------------- conv3: y2 NHWC [8,8,128] -> flat NHWC [16,256] ----------------
__global__ __launch_bounds__(256) void conv3_kernel(
    const float* __restrict__ y2, const float* __restrict__ w3t,
    const float* __restrict__ b3, float* __restrict__ flat)
{
    __shared__ float y2p[9][9][128];     // padded, 41.5 KB
    const int t = threadIdx.x;
    const int n = blockIdx.x;
    for (int i = t; i < 9 * 9 * 128; i += 256) ((float*)y2p)[i] = 0.0f;
    __syncthreads();
    const float4* src = (const float4*)(y2 + (size_t)n * 8192);
    for (int i = t; i < 2048; i += 256) {
        int p = i >> 5, c = i & 31;
        int ih = p >> 3, iw = p & 7;
        ((float4*)&y2p[ih + 1][iw + 1][0])[c] = src[i];
    }
    __syncthreads();
    const int co4 = t & 63;              // co = co4*4 over 256
    const int pg  = t >> 6;              // 0..3, pixels pg*4..pg*4+3 of 16
    float4 acc[4];
    float4 bias = ((const float4*)b3)[co4];
    #pragma unroll
    for (int j = 0; j < 4; ++j) acc[j] = bias;
    #pragma unroll
    for (int kh = 0; kh < 3; ++kh)
    #pragma unroll
    for (int kw = 0; kw < 3; ++kw) {
        #pragma unroll 4
        for (int c4 = 0; c4 < 32; ++c4) {
            const float4* wp = (const float4*)w3t + ((kh * 3 + kw) * 128 + c4 * 4) * 64;
            float4 w0 = wp[co4];
            float4 w1v = wp[64 + co4];
            float4 w2v = wp[128 + co4];
            float4 w3v = wp[192 + co4];
            #pragma unroll
            for (int j = 0; j < 4; ++j) {
                int p = pg * 4 + j;
                int oh = p >> 2, ow = p & 3;
                float4 f = ((const float4*)&y2p[2 * oh + kh][2 * ow + kw][0])[c4];
                acc[j].x += f.x * w0.x + f.y * w1v.x + f.z * w2v.x + f.w * w3v.x;
                acc[j].y += f.x * w0.y + f.y * w1v.y + f.z * w2v.y + f.w * w3v.y;
                acc[j].z += f.x * w0.z + f.y * w1v.z + f.z * w2v.z + f.w * w3v.z;
                acc[j].w += f.x * w0.w + f.y * w1v.w + f.z * w2v.w + f.w * w3v.w;
            }
        }
    }
    #pragma unroll
    for (int j = 0; j < 4; ++j) {
        int p = pg * 4 + j;
        float4 v = acc[j];
        v.x = fmaxf(v.x, 0.f); v.y = fmaxf(v.y, 0.f);
        v.z = fmaxf(v.z, 0.f); v.w = fmaxf(v.w, 0.f);
        ((float4*)(flat + ((size_t)n * 16 + p) * 256))[co4] = v;
    }
}

// ---------------- VQ: nearest code + counts + loss partials ----------------
__global__ __launch_bounds__(256) void vq_kernel(
    const float* __restrict__ flat, const float* __restrict__ codesT,
    const float* __restrict__ cnorm, const int* __restrict__ idxp,
    int* __restrict__ enc_idx, int* __restrict__ counts,
    float* __restrict__ loss_sum)
{
    __shared__ float fs[32 * 256];       // 32 rows, 32 KB
    __shared__ float bv[32 * 16];
    __shared__ int   bi[32 * 16];
    __shared__ float red[32];
    const int t = threadIdx.x;
    const int n0 = blockIdx.x * 32;
    const int Kc = (idxp[0] == 0) ? 512 : 1024;
    for (int i = t; i < 2048; i += 256)
        ((float4*)fs)[i] = ((const float4*)(flat + (size_t)n0 * 256))[i];
    __syncthreads();
    const int kq = t & 15, rq = t >> 4;  // 2 rows x 4 codes per thread
    float bestv0 = 3.0e38f, bestv1 = 3.0e38f;
    int   besti0 = 0, besti1 = 0;
    const int npass = Kc >> 6;
    const float* fr0 = fs + (rq * 2 + 0) * 256;
    const float* fr1 = fs + (rq * 2 + 1) * 256;
    for (int pass = 0; pass < npass; ++pass) {
        const int cbase = pass * 64 + kq * 4;
        float4 d0 = {0, 0, 0, 0}, d1 = {0, 0, 0, 0};
        #pragma unroll 4
        for (int c4 = 0; c4 < 64; ++c4) {
            float4 cw0 = *(const float4*)(codesT + (size_t)(c4 * 4 + 0) * 1024 + cbase);
            float4 cw1 = *(const float4*)(codesT + (size_t)(c4 * 4 + 1) * 1024 + cbase);
            float4 cw2 = *(const float4*)(codesT + (size_t)(c4 * 4 + 2) * 1024 + cbase);
            float4 cw3 = *(const float4*)(codesT + (size_t)(c4 * 4 + 3) * 1024 + cbase);
            float4 f0 = ((const float4*)fr0)[c4];
            float4 f1 = ((const float4*)fr1)[c4];
            d0.x += f0.x * cw0.x + f0.y * cw1.x + f0.z * cw2.x + f0.w * cw3.x;
            d0.y += f0.x * cw0.y + f0.y * cw1.y + f0.z * cw2.y + f0.w * cw3.y;
            d0.z += f0.x * cw0.z + f0.y * cw1.z + f0.z * cw2.z + f0.w * cw3.z;
            d0.w += f0.x * cw0.w + f0.y * cw1.w + f0.z * cw2.w + f0.w * cw3.w;
            d1.x += f1.x * cw0.x + f1.y * cw1.x + f1.z * cw2.x + f1.w * cw3.x;
            d1.y += f1.x * cw0.y + f1.y * cw1.y + f1.z * cw2.y + f1.w * cw3.y;
            d1.z += f1.x * cw0.z + f1.y * cw1.z + f1.z * cw2.z + f1.w * cw3.z;
            d1.w += f1.x * cw0.w + f1.y * cw1.w + f1.z * cw2.w + f1.w * cw3.w;
        }
        float4 cn = *(const float4*)(cnorm + cbase);
        float s;
        s = cn.x - 2.f * d0.x; if (s < bestv0) { bestv0 = s; besti0 = cbase; }
        s = cn.y - 2.f * d0.y; if (s < bestv0) { bestv0 = s; besti0 = cbase + 1; }
        s = cn.z - 2.f * d0.z; if (s < bestv0) { bestv0 = s; besti0 = cbase + 2; }
        s = cn.w - 2.f * d0.w; if (s < bestv0) { bestv0 = s; besti0 = cbase + 3; }
        s = cn.x - 2.f * d1.x; if (s < bestv1) { bestv1 = s; besti1 = cbase; }
        s = cn.y - 2.f * d1.y; if (s < bestv1) { bestv1 = s; besti1 = cbase + 1; }
        s = cn.z - 2.f * d1.z; if (s < bestv1) { bestv1 = s; besti1 = cbase + 2; }
        s = cn.w - 2.f * d1.w; if (s < bestv1) { bestv1 = s; besti1 = cbase + 3; }
    }
    bv[(rq * 2 + 0) * 16 + kq] = bestv0; bi[(rq * 2 + 0) * 16 + kq] = besti0;
    bv[(rq * 2 + 1) * 16 + kq] = bestv1; bi[(rq * 2 + 1) * 16 + kq] = besti1;
    __syncthreads();
    if (t < 32) {
        float bval = 3.0e38f; int bidx = 1 << 30;
        for (int k = 0; k < 16; ++k) {
            float v = bv[t * 16 + k]; int ii = bi[t * 16 + k];
            if (v < bval || (v == bval && ii < bidx)) { bval = v; bidx = ii; }
        }
        enc_idx[n0 + t] = bidx;
        atomicAdd(&counts[bidx], 1);
        float fn = 0.0f;
        const float4* fr = (const float4*)(fs + t * 256);
        for (int i = 0; i < 64; ++i) {
            float4 v = fr[i];
            fn += v.x * v.x + v.y * v.y + v.z * v.z + v.w * v.w;
        }
        red[t] = fn + bval;              // ||q - f||^2 for this row
    }
    __syncthreads();
    if (t < 16) red[t] += red[t + 16];
    __syncthreads();
    if (t < 8) red[t] += red[t + 8];
    __syncthreads();
    if (t < 4) red[t] += red[t + 4];
    __syncthreads();
    if (t < 2) red[t] += red[t + 2];
    __syncthreads();
    if (t == 0) atomicAdd(loss_sum, red[0] + red[1]);
}

// ---------------- q_fea gather: [n][c*16+hw] = codes[best[n,hw]][c] ----------------
__global__ __launch_bounds__(256) void qfea_kernel(
    const int* __restrict__ enc_idx, const float* __restrict__ code0,
    const float* __restrict__ code1, float* __restrict__ qfea)
{
    __shared__ int bests[16];
    __shared__ float qs[16][257];
    const int t = threadIdx.x;
    const int n = blockIdx.x;
    if (t < 16) bests[t] = enc_idx[n * 16 + t];
    __syncthreads();
    for (int hw = 0; hw < 16; ++hw) {
        int k = bests[hw];
        const float* c = (k < 512) ? code0 + (size_t)k * 256
                                   : code1 + (size_t)(k - 512) * 256;
        qs[hw][t] = c[t];
    }
    __syncthreads();
    float* dst = qfea + (size_t)n * 4096;
    for (int i = 0; i < 16; ++i) {
        int o = i * 256 + t;
        dst[o] = qs[o & 15][o >> 4];
    }
}

__device__ inline float gelu_tanh(float x) {
    float x3 = x * x * x;
    float u = 0.7978845608028654f * (x + 0.044715f * x3);
    return 0.5f * x * (1.0f + tanhf(u));
}

// ---------------- fc1: h = gelu(q_fea @ fc1_w^T + b), 64x64 tiles ----------------
__global__ __launch_bounds__(256) void fc1_kernel(
    const float* __restrict__ qfea, const float* __restrict__ fc1t,
    const float* __restrict__ fc1b, float* __restrict__ h)
{
    __shared__ float As[64 * 68];
    __shared__ float Bs[64 * 68];
    const int t = threadIdx.x;
    const int bn = blockIdx.x & 63;      // 64 row tiles
    const int bo = blockIdx.x >> 6;      // 8 col tiles
    const int kq = t & 15, rq = t >> 4;
    float4 acc[4] = {{0,0,0,0},{0,0,0,0},{0,0,0,0},{0,0,0,0}};
    for (int kt = 0; kt < 64; ++kt) {
        #pragma unroll
        for (int ii = 0; ii < 4; ++ii) {
            int i = t + 256 * ii;
            int r = i >> 4, k4 = (i & 15) << 2;
            *(float4*)&As[r * 68 + k4] =
                *(const float4*)(qfea + (size_t)(bn * 64 + r) * 4096 + kt * 64 + k4);
            *(float4*)&Bs[r * 68 + k4] =
                *(const float4*)(fc1t + (size_t)(kt * 64 + r) * 512 + bo * 64 + k4);
        }
        __syncthreads();
        #pragma unroll 4
        for (int c4 = 0; c4 < 16; ++c4) {
            float4 b0 = *(const float4*)&Bs[(c4 * 4 + 0) * 68 + kq * 4];
            float4 b1v = *(const float4*)&Bs[(c4 * 4 + 1) * 68 + kq * 4];
            float4 b2v = *(const float4*)&Bs[(c4 * 4 + 2) * 68 + kq * 4];
            float4 b3v = *(const float4*)&Bs[(c4 * 4 + 3) * 68 + kq * 4];
            #pragma unroll
            for (int r = 0; r < 4; ++r) {
                float4 f = *(const float4*)&As[(rq * 4 + r) * 68 + c4 * 4];
                acc[r].x += f.x * b0.x + f.y * b1v.x + f.z * b2v.x + f.w * b3v.x;
                acc[r].y += f.x * b0.y + f.y * b1v.y + f.z * b2v.y + f.w * b3v.y;
                acc[r].z += f.x * b0.z + f.y * b1v.z + f.z * b2v.z + f.w * b3v.z;
                acc[r].w += f.x * b0.w + f.y * b1v.w + f.z * b2v.w + f.w * b3v.w;
            }
        }
        __syncthreads();
    }
    float4 bias = ((const float4*)(fc1b + bo * 64))[kq];
    #pragma unroll
    for (int r = 0; r < 4; ++r) {
        float4 v = acc[r];
        v.x = gelu_tanh(v.x + bias.x);
        v.y = gelu_tanh(v.y + bias.y);
        v.z = gelu_tanh(v.z + bias.z);
        v.w = gelu_tanh(v.w + bias.w);
        *(float4*)(h + (size_t)(bn * 64 + rq * 4 + r) * 512 + bo * 64 + kq * 4) = v;
    }
}

// ---------------- fc2: out = h @ fc2_w^T + b (wave per row) ----------------
__global__ __launch_bounds__(256) void fc2_kernel(
    const float* __restrict__ h, const float* __restrict__ fc2w,
    const float* __restrict__ fc2b, float* __restrict__ out)
{
    __shared__ float ws2[10 * 512];
    const int t = threadIdx.x;
    for (int i = t; i < 5120; i += 256) ws2[i] = fc2w[i];
    __syncthreads();
    const int lane = t & 63, wv = t >> 6;
    const int n = blockIdx.x * 4 + wv;
    float acc[10];
    #pragma unroll
    for (int j = 0; j < 10; ++j) acc[j] = 0.f;
    #pragma unroll
    for (int i = 0; i < 8; ++i) {
        float hv = h[(size_t)n * 512 + lane + 64 * i];
        #pragma unroll
        for (int j = 0; j < 10; ++j) acc[j] += hv * ws2[j * 512 + lane + 64 * i];
    }
    #pragma unroll
    for (int j = 0; j < 10; ++j) {
        float v = acc[j];
        for (int off = 32; off; off >>= 1) v += __shfl_down(v, off);
        if (lane == 0) out[(size_t)n * 10 + j] = v + fc2b[j];
    }
}

// ---------------- finalize: loss + perplexity ----------------
__global__ __launch_bounds__(256) void finalize_kernel(
    const int* __restrict__ counts, const float* __restrict__ loss_sum,
    const int* __restrict__ idxp, float* __restrict__ out)
{
    __shared__ float red[256];
    const int t = threadIdx.x;
    const int Kc = (idxp[0] == 0) ? 512 : 1024;
    float s = 0.f;
    for (int k = t; k < Kc; k += 256) {
        float p = (float)counts[k] * (1.0f / 65536.0f);
        s += p * logf(p + 1e-10f);
    }
    red[t] = s;
    __syncthreads();
    for (int o = 128; o; o >>= 1) {
        if (t < o) red[t] += red[t + o];
        __syncthreads();
    }
    if (t == 0) {
        out[40960] = loss_sum[0] * (1.25f / 16777216.0f);  // (1 + 0.25) * mean
        out[40961] = expf(-red[0]);
    }
}

// ---------------- launch ----------------
extern "C" void kernel_launch(void* const* d_in, const int* in_sizes, int n_in,
                              void* d_out, int out_size, void* d_ws, size_t ws_size,
                              hipStream_t stream)
{
    const float* x     = (const float*)d_in[0];
    const float* w1    = (const float*)d_in[1];
    const float* b1    = (const float*)d_in[2];
    const float* w2    = (const float*)d_in[3];
    const float* b2    = (const float*)d_in[4];
    const float* w3    = (const float*)d_in[5];
    const float* b3    = (const float*)d_in[6];
    const float* code0 = (const float*)d_in[7];
    const float* code1 = (const float*)d_in[8];
    const float* fc1w  = (const float*)d_in[9];
    const float* fc1b  = (const float*)d_in[10];
    const float* fc2w  = (const float*)d_in[11];
    const float* fc2b  = (const float*)d_in[12];
    const int*   idxp  = (const int*)d_in[13];
    float* out = (float*)d_out;
    char* ws = (char*)d_ws;

    float* w1t    = (float*)(ws + OFF_W1T);
    float* w2t    = (float*)(ws + OFF_W2T);
    float* w3t    = (float*)(ws + OFF_W3T);
    float* codesT = (float*)(ws + OFF_CODEST);
    float* cnorm  = (float*)(ws + OFF_CNORM);
    float* fc1t   = (float*)(ws + OFF_FC1T);
    int*   counts = (int*)(ws + OFF_COUNTS);
    float* lsum   = (float*)(ws + OFF_LOSS);
    int*   enc    = (int*)(ws + OFF_ENC);
    float* y2     = (float*)(ws + OFF_Y2);     // conv2 out; dead after conv3
    float* flat   = (float*)(ws + OFF_FLAT);   // conv3 out; dead after vq
    float* qfea   = (float*)(ws + OFF_Y2);     // alias y2
    float* h      = (float*)(ws + OFF_FLAT);   // alias flat

    prep_kernel<<<10671, 256, 0, stream>>>(w1, w2, w3, code0, code1, fc1w, idxp,
                                           w1t, w2t, w3t, codesT, cnorm, fc1t,
                                           counts, lsum);
    conv12_kernel<<<8192, 256, 0, stream>>>(x, w1t, b1, w2t, b2, y2);
    conv3_kernel<<<4096, 256, 0, stream>>>(y2, w3t, b3, flat);
    vq_kernel<<<2048, 256, 0, stream>>>(flat, codesT, cnorm, idxp, enc, counts, lsum);
    qfea_kernel<<<4096, 256, 0, stream>>>(enc, code0, code1, qfea);
    fc1_kernel<<<512, 256, 0, stream>>>(qfea, fc1t, fc1b, h);
    fc2_kernel<<<1024, 256, 0, stream>>>(h, fc2w, fc2b, out);
    finalize_kernel<<<1, 256, 0, stream>>>(counts, lsum, idxp, out);
}

// Round 2
// 1644.300 us; speedup vs baseline: 2.3498x; 2.3498x over previous
//
#include <hip/hip_runtime.h>
#include <math.h>

// ============================ MFMA types/helpers ============================
typedef short bf16x8 __attribute__((ext_vector_type(8)));   // 8 bf16 (4 VGPRs)
typedef float f32x4 __attribute__((ext_vector_type(4)));

#define MFMA16(a, b, c) __builtin_amdgcn_mfma_f32_16x16x32_bf16((a), (b), (c), 0, 0, 0)

__device__ inline unsigned short bf16_rn(float x) {
    unsigned u = __float_as_uint(x);
    unsigned r = u + 0x7FFFu + ((u >> 16) & 1u);
    return (unsigned short)(r >> 16);
}
__device__ inline float bf16_to_f(unsigned short h) {
    return __uint_as_float(((unsigned)h) << 16);
}
__device__ inline void split2(float x, unsigned short* hp, unsigned short* lp) {
    unsigned short h = bf16_rn(x);
    *hp = h;
    *lp = bf16_rn(x - bf16_to_f(h));
}

// ============================ workspace layout (bytes) ============================
// total = 204,128,512  (< 212,515,840 proven available in round 1)
static constexpr size_t OFF_W1SH  = 0;           // [64co][32k] shorts  (k 27..31 zero)
static constexpr size_t OFF_W1SL  = 4096;
static constexpr size_t OFF_W2SH  = 8192;        // [128co][576k] shorts, k = khw*64+ci
static constexpr size_t OFF_W2SL  = 155648;
static constexpr size_t OFF_W3SH  = 303104;      // [256co][1152k] shorts, k = khw*128+ci
static constexpr size_t OFF_W3SL  = 892928;
static constexpr size_t OFF_CODH  = 1482752;     // [1024][256] shorts (rows>=Kc zero)
static constexpr size_t OFF_CODL  = 2007040;
static constexpr size_t OFF_CNORM = 2531328;     // [1024] f32 (3e38 for >=Kc)
static constexpr size_t OFF_COUNTS= 2535424;     // [1024] int
static constexpr size_t OFF_LOSS  = 2539520;     // f32
static constexpr size_t OFF_ENC   = 2539776;     // [65536] int
static constexpr size_t OFF_BIG   = 2801920;     // y2h(67108864)+y2l(67108864)
                                                 // post-conv3 reuse: LUT f32 (33554432) + h f32 (8388608)
static constexpr size_t OFF_FLATS = 137019648;   // fh(33554432)+fl(33554432)
                                                 // post-vq reuse: fc1wsh(4194304)+fc1wsl(4194304)

// ============================ prep1: weight/code splits ============================
__global__ __launch_bounds__(256) void prep1_kernel(
    const float* __restrict__ w1, const float* __restrict__ w2,
    const float* __restrict__ w3, const float* __restrict__ code0,
    const float* __restrict__ code1, const int* __restrict__ idxp,
    unsigned short* __restrict__ w1sh, unsigned short* __restrict__ w1sl,
    unsigned short* __restrict__ w2sh, unsigned short* __restrict__ w2sl,
    unsigned short* __restrict__ w3sh, unsigned short* __restrict__ w3sl,
    unsigned short* __restrict__ codh, unsigned short* __restrict__ codl,
    float* __restrict__ cnorm, int* __restrict__ counts, float* __restrict__ lsum)
{
    int i = blockIdx.x * 256 + threadIdx.x;
    const int Kc = (idxp[0] == 0) ? 512 : 1024;
    if (i < 2048) {                           // w1s [co][32], k=(kh*3+kw)*3+ci
        int co = i >> 5, k = i & 31;
        float v = 0.f;
        if (k < 27) {
            int khw = k / 3, ci = k - khw * 3;
            v = w1[(co * 3 + ci) * 9 + khw];
        }
        unsigned short h, l; split2(v, &h, &l);
        w1sh[i] = h; w1sl[i] = l; return;
    }
    i -= 2048;
    if (i < 73728) {                          // w2s [co][576], k=khw*64+ci
        int co = i / 576, k = i - co * 576;
        int khw = k >> 6, ci = k & 63;
        float v = w2[(co * 64 + ci) * 9 + khw];
        unsigned short h, l; split2(v, &h, &l);
        w2sh[i] = h; w2sl[i] = l; return;
    }
    i -= 73728;
    if (i < 294912) {                         // w3s [co][1152], k=khw*128+ci
        int co = i / 1152, k = i - co * 1152;
        int khw = k >> 7, ci = k & 127;
        float v = w3[(co * 128 + ci) * 9 + khw];
        unsigned short h, l; split2(v, &h, &l);
        w3sh[i] = h; w3sl[i] = l; return;
    }
    i -= 294912;
    if (i < 262144) {                         // codes [code][256]
        int code = i >> 8, c = i & 255;
        float v = 0.f;
        if (code < Kc) v = (code < 512) ? code0[code * 256 + c]
                                        : code1[(code - 512) * 256 + c];
        unsigned short h, l; split2(v, &h, &l);
        codh[i] = h; codl[i] = l; return;
    }
    i -= 262144;
    if (i < 1024) {                           // cnorm (exact fp32)
        float s;
        if (i < Kc) {
            const float* c = (i < 512) ? code0 + (size_t)i * 256
                                       : code1 + (size_t)(i - 512) * 256;
            s = 0.f;
            for (int k = 0; k < 256; ++k) s += c[k] * c[k];
        } else s = 3.0e38f;
        cnorm[i] = s; return;
    }
    i -= 1024;
    if (i < 1024) { counts[i] = 0; return; }
    i -= 1024;
    if (i == 0) lsum[0] = 0.f;
}

// ============================ conv12: fused conv1+conv2 (split-bf16 MFMA) ============================
// block = half image (4 conv2-out rows). LDS:
//   [0,44064): y1h[(l*17+c)*72+ci] (22032) + y1l (22032); xsp f32[3][34][34] aliases first 13872 B
//   [44064,62496): Ah1[4][144][8] (9216) + Al1 (9216)   (conv1 im2col, quad-major)
__global__ __launch_bounds__(256, 2) void conv12_kernel(
    const float* __restrict__ x,
    const unsigned short* __restrict__ w1sh, const unsigned short* __restrict__ w1sl,
    const float* __restrict__ b1,
    const unsigned short* __restrict__ w2sh, const unsigned short* __restrict__ w2sl,
    const float* __restrict__ b2,
    unsigned short* __restrict__ y2h, unsigned short* __restrict__ y2l)
{
    __shared__ __align__(16) char smem[62496];
    float* xsp = (float*)smem;
    unsigned short* y1h = (unsigned short*)smem;
    unsigned short* y1l = (unsigned short*)(smem + 22032);
    unsigned short* Ah1 = (unsigned short*)(smem + 44064);
    unsigned short* Al1 = (unsigned short*)(smem + 53280);
    const int t = threadIdx.x;
    const int n = blockIdx.x >> 1, hh = blockIdx.x & 1;
    const int wv = t >> 6, lane = t & 63, lq = lane >> 4, lm = lane & 15;

    // ---- load x into padded LDS ----
    for (int i = t; i < 3468; i += 256) xsp[i] = 0.f;
    __syncthreads();
    const float* xn = x + (size_t)n * 3072;
    for (int i = t; i < 768; i += 256) {
        float4 v = ((const float4*)xn)[i];
        int ci = i >> 8, rem = i & 255, ih = rem >> 3, iw = (rem & 7) << 2;
        float* d = xsp + (size_t)(ci * 34 + ih + 1) * 34 + iw + 1;
        d[0] = v.x; d[1] = v.y; d[2] = v.z; d[3] = v.w;
    }
    __syncthreads();

    // ---- conv1 im2col: A[px=l*16+ow][k] (l 0..8, k 0..31; k>=27 or invalid row -> 0) ----
    for (int i = t; i < 4608; i += 256) {
        int px = i >> 5, k = i & 31;
        int l = px >> 4, ow = px & 15;
        float v = 0.f;
        if (k < 27 && !(hh == 0 && l == 0)) {
            int khw = k / 3, ci = k - khw * 3;
            int kh = khw / 3, kw = khw - kh * 3;
            int xr = 16 * hh - 2 + 2 * l + kh;      // padded row idx
            int xc = 2 * ow + kw;                   // padded col idx
            v = xsp[(size_t)(ci * 34 + xr) * 34 + xc];
        }
        unsigned short vh, vl; split2(v, &vh, &vl);
        int q = k >> 3, j = k & 7;
        Ah1[(q * 144 + px) * 8 + j] = vh;
        Al1[(q * 144 + px) * 8 + j] = vl;
    }
    __syncthreads();   // xsp dead; y1 region reusable

    // ---- zero y1 pads: row l==0 (c 0..16) fully + column c==0 of rows 1..8 ----
    {
        unsigned* zh = (unsigned*)y1h; unsigned* zl = (unsigned*)y1l;
        for (int i = t; i < 612; i += 256) { zh[i] = 0u; zl[i] = 0u; }         // l=0, 17*72 shorts
        for (int i = t; i < 288; i += 256) {
            int l = 1 + i / 36, d = i - (l - 1) * 36;
            zh[l * 612 + d] = 0u; zl[l * 612 + d] = 0u;                        // (l*17+0)*72 shorts
        }
    }
    __syncthreads();

    // ---- conv1 via MFMA: wave -> co group wv*16; 9 m-tiles of 16 px ----
    {
        f32x4 acc[9];
        #pragma unroll
        for (int mt = 0; mt < 9; ++mt) acc[mt] = (f32x4){0.f, 0.f, 0.f, 0.f};
        int co = wv * 16 + lm;
        bf16x8 bh = *(const bf16x8*)(w1sh + co * 32 + lq * 8);
        bf16x8 bl = *(const bf16x8*)(w1sl + co * 32 + lq * 8);
        #pragma unroll
        for (int mt = 0; mt < 9; ++mt) {
            bf16x8 ah = *(const bf16x8*)(Ah1 + (lq * 144 + mt * 16 + lm) * 8);
            bf16x8 al = *(const bf16x8*)(Al1 + (lq * 144 + mt * 16 + lm) * 8);
            acc[mt] = MFMA16(ah, bh, acc[mt]);
            acc[mt] = MFMA16(ah, bl, acc[mt]);
            acc[mt] = MFMA16(al, bh, acc[mt]);
        }
        float bias = b1[co];
        #pragma unroll
        for (int mt = 0; mt < 9; ++mt) {
            #pragma unroll
            for (int r = 0; r < 4; ++r) {
                int px = mt * 16 + lq * 4 + r;
                int l = px >> 4, ow = px & 15;
                if (hh == 0 && l == 0) continue;
                float v = fmaxf(acc[mt][r] + bias, 0.f);
                unsigned short vh, vl; split2(v, &vh, &vl);
                y1h[(l * 17 + ow + 1) * 72 + co] = vh;
                y1l[(l * 17 + ow + 1) * 72 + co] = vl;
            }
        }
    }
    __syncthreads();

    // ---- conv2 via MFMA: wave = (m-tile wv>>1, n-half wv&1); M=32 px, N=128, K=576 ----
    {
        const int mt2 = wv >> 1, nh = wv & 1;
        f32x4 acc[4];
        #pragma unroll
        for (int i = 0; i < 4; ++i) acc[i] = (f32x4){0.f, 0.f, 0.f, 0.f};
        int px = mt2 * 16 + lm;
        int ohl = px >> 3, ow2 = px & 7;
        #pragma unroll
        for (int ks = 0; ks < 18; ++ks) {
            int khw = ks >> 1;
            int kh = khw / 3, kw = khw - kh * 3;
            int ci0 = (ks & 1) * 32 + lq * 8;
            int l = 2 * ohl + kh, c = 2 * ow2 + kw;
            bf16x8 ah = *(const bf16x8*)(y1h + (l * 17 + c) * 72 + ci0);
            bf16x8 al = *(const bf16x8*)(y1l + (l * 17 + c) * 72 + ci0);
            #pragma unroll
            for (int nt = 0; nt < 4; ++nt) {
                int co = nh * 64 + nt * 16 + lm;
                bf16x8 bh = *(const bf16x8*)(w2sh + co * 576 + ks * 32 + lq * 8);
                bf16x8 bl = *(const bf16x8*)(w2sl + co * 576 + ks * 32 + lq * 8);
                acc[nt] = MFMA16(ah, bh, acc[nt]);
                acc[nt] = MFMA16(ah, bl, acc[nt]);
                acc[nt] = MFMA16(al, bh, acc[nt]);
            }
        }
        #pragma unroll
        for (int nt = 0; nt < 4; ++nt) {
            int co = nh * 64 + nt * 16 + lm;
            float bias = b2[co];
            #pragma unroll
            for (int r = 0; r < 4; ++r) {
                int pxr = mt2 * 16 + lq * 4 + r;
                int ohr = pxr >> 3, owr = pxr & 7;
                float v = fmaxf(acc[nt][r] + bias, 0.f);
                unsigned short vh, vl; split2(v, &vh, &vl);
                size_t o = ((size_t)n * 64 + (hh * 4 + ohr) * 8 + owr) * 128 + co;
                y2h[o] = vh; y2l[o] = vl;
            }
        }
    }
}

// ============================ conv3: implicit GEMM 128px x 256co, K=1152 ============================
__global__ __launch_bounds__(256, 2) void conv3_kernel(
    const unsigned short* __restrict__ y2h, const unsigned short* __restrict__ y2l,
    const unsigned short* __restrict__ w3sh, const unsigned short* __restrict__ w3sl,
    const float* __restrict__ b3,
    unsigned short* __restrict__ fh, unsigned short* __restrict__ fl)
{
    __shared__ __align__(16) unsigned short Ah[4 * 128 * 8];   // [q][px][8]
    __shared__ __align__(16) unsigned short Al[4 * 128 * 8];
    const int t = threadIdx.x, b = blockIdx.x;
    const int wv = t >> 6, lane = t & 63, lq = lane >> 4, lm = lane & 15;
    const int mh = wv >> 1, nh = wv & 1;
    f32x4 acc[4][8];
    #pragma unroll
    for (int i = 0; i < 4; ++i)
        #pragma unroll
        for (int j = 0; j < 8; ++j) acc[i][j] = (f32x4){0.f, 0.f, 0.f, 0.f};
    const int gpx = t >> 1, gsel = t & 1;
    const int gimg = b * 8 + (gpx >> 4);
    const int gp = gpx & 15, goh = gp >> 2, gow = gp & 3;
    const unsigned short* gsrc = gsel ? y2l : y2h;
    unsigned short* gdst = gsel ? Al : Ah;

    for (int ks = 0; ks < 36; ++ks) {
        __syncthreads();
        {
            int khw = ks >> 2;
            int kh = khw / 3, kw = khw - kh * 3;
            int ci0 = (ks & 3) * 32;
            int ih = 2 * goh + kh - 1, iw = 2 * gow + kw - 1;
            if (ih >= 0 && ih < 8 && iw >= 0 && iw < 8) {
                const unsigned short* s = gsrc + ((size_t)gimg * 64 + ih * 8 + iw) * 128 + ci0;
                #pragma unroll
                for (int qq = 0; qq < 4; ++qq)
                    *(bf16x8*)(gdst + (qq * 128 + gpx) * 8) = *(const bf16x8*)(s + qq * 8);
            } else {
                #pragma unroll
                for (int qq = 0; qq < 4; ++qq)
                    *(bf16x8*)(gdst + (qq * 128 + gpx) * 8) = (bf16x8){0, 0, 0, 0, 0, 0, 0, 0};
            }
        }
        __syncthreads();
        bf16x8 ah[4], al[4];
        #pragma unroll
        for (int mt = 0; mt < 4; ++mt) {
            int mloc = mh * 64 + mt * 16 + lm;
            ah[mt] = *(const bf16x8*)(Ah + (lq * 128 + mloc) * 8);
            al[mt] = *(const bf16x8*)(Al + (lq * 128 + mloc) * 8);
        }
        #pragma unroll
        for (int nt = 0; nt < 8; ++nt) {
            int co = nh * 128 + nt * 16 + lm;
            bf16x8 bh = *(const bf16x8*)(w3sh + (size_t)co * 1152 + ks * 32 + lq * 8);
            bf16x8 bl = *(const bf16x8*)(w3sl + (size_t)co * 1152 + ks * 32 + lq * 8);
            #pragma unroll
            for (int mt = 0; mt < 4; ++mt) {
                acc[mt][nt] = MFMA16(ah[mt], bh, acc[mt][nt]);
                acc[mt][nt] = MFMA16(ah[mt], bl, acc[mt][nt]);
                acc[mt][nt] = MFMA16(al[mt], bh, acc[mt][nt]);
            }
        }
    }
    #pragma unroll
    for (int nt = 0; nt < 8; ++nt) {
        int co = nh * 128 + nt * 16 + lm;
        float bias = b3[co];
        #pragma unroll
        for (int mt = 0; mt < 4; ++mt) {
            #pragma unroll
            for (int r = 0; r < 4; ++r) {
                int mloc = mh * 64 + mt * 16 + lq * 4 + r;
                size_t row = (size_t)b * 128 + mloc;
                float v = fmaxf(acc[mt][nt][r] + bias, 0.f);
                unsigned short vh, vl; split2(v, &vh, &vl);
                fh[row * 256 + co] = vh;
                fl[row * 256 + co] = vl;
            }
        }
    }
}

// ============================ vq: fused distance GEMM + argmin + loss ============================
// block = 128 rows; wave = 32 rows, A-frags in registers (full K=256); codes staged 32/chunk.
__global__ __launch_bounds__(256, 2) void vq_kernel(
    const unsigned short* __restrict__ fh, const unsigned short* __restrict__ fl,
    const unsigned short* __restrict__ codh, const unsigned short* __restrict__ codl,
    const float* __restrict__ cnorm, int* __restrict__ enc,
    int* __restrict__ counts, float* __restrict__ lsum)
{
    __shared__ __align__(16) unsigned short Bh[32 * 256];   // [kc][code32][8]
    __shared__ __align__(16) unsigned short Bl[32 * 256];
    __shared__ float fnbuf[4 * 32];
    const int t = threadIdx.x;
    const int wv = t >> 6, lane = t & 63, lq = lane >> 4, lm = lane & 15;
    const int r0 = blockIdx.x * 128 + wv * 32;

    bf16x8 ah[2][8], al[2][8];
    #pragma unroll
    for (int mt = 0; mt < 2; ++mt)
        #pragma unroll
        for (int ks = 0; ks < 8; ++ks) {
            size_t base = ((size_t)(r0 + mt * 16 + lm)) * 256 + ks * 32 + lq * 8;
            ah[mt][ks] = *(const bf16x8*)(fh + base);
            al[mt][ks] = *(const bf16x8*)(fl + base);
        }
    // ||f||^2 per row (reduce over the 4 k-quads)
    #pragma unroll
    for (int mt = 0; mt < 2; ++mt) {
        float s = 0.f;
        #pragma unroll
        for (int ks = 0; ks < 8; ++ks)
            #pragma unroll
            for (int j = 0; j < 8; ++j) {
                float v = bf16_to_f((unsigned short)ah[mt][ks][j]) +
                          bf16_to_f((unsigned short)al[mt][ks][j]);
                s += v * v;
            }
        s += __shfl_xor(s, 16);
        s += __shfl_xor(s, 32);
        if (lq == 0) fnbuf[wv * 32 + mt * 16 + lm] = s;
    }
    float bv[2][4]; int bi[2][4];
    #pragma unroll
    for (int mt = 0; mt < 2; ++mt)
        #pragma unroll
        for (int r = 0; r < 4; ++r) { bv[mt][r] = 3.0e38f; bi[mt][r] = 0; }

    for (int ch = 0; ch < 32; ++ch) {
        __syncthreads();
        #pragma unroll
        for (int uu = 0; uu < 4; ++uu) {      // stage 32 codes x 256 k (conflict-free dst)
            int u = t * 4 + uu;
            int kc = u >> 5, row = u & 31;
            size_t src = ((size_t)(ch * 32 + row)) * 256 + kc * 8;
            *(bf16x8*)(Bh + u * 8) = *(const bf16x8*)(codh + src);
            *(bf16x8*)(Bl + u * 8) = *(const bf16x8*)(codl + src);
        }
        __syncthreads();
        f32x4 acc[2][2];
        #pragma unroll
        for (int i = 0; i < 2; ++i)
            #pragma unroll
            for (int j = 0; j < 2; ++j) acc[i][j] = (f32x4){0.f, 0.f, 0.f, 0.f};
        #pragma unroll
        for (int nt = 0; nt < 2; ++nt) {
            #pragma unroll
            for (int ks = 0; ks < 8; ++ks) {
                int kc = ks * 4 + lq;
                bf16x8 bh = *(const bf16x8*)(Bh + (kc * 32 + nt * 16 + lm) * 8);
                bf16x8 bl = *(const bf16x8*)(Bl + (kc * 32 + nt * 16 + lm) * 8);
                acc[0][nt] = MFMA16(ah[0][ks], bh, acc[0][nt]);
                acc[0][nt] = MFMA16(ah[0][ks], bl, acc[0][nt]);
                acc[0][nt] = MFMA16(al[0][ks], bh, acc[0][nt]);
                acc[1][nt] = MFMA16(ah[1][ks], bh, acc[1][nt]);
                acc[1][nt] = MFMA16(ah[1][ks], bl, acc[1][nt]);
                acc[1][nt] = MFMA16(al[1][ks], bh, acc[1][nt]);
            }
        }
        #pragma unroll
        for (int nt = 0; nt < 2; ++nt) {
            int code = ch * 32 + nt * 16 + lm;
            float cn = cnorm[code];
            #pragma unroll
            for (int mt = 0; mt < 2; ++mt)
                #pragma unroll
                for (int r = 0; r < 4; ++r) {
                    float d = cn - 2.f * acc[mt][nt][r];
                    if (d < bv[mt][r]) { bv[mt][r] = d; bi[mt][r] = code; }
                }
        }
    }
    // reduce over the 16 column-lanes (lexicographic: value, then smaller index)
    #pragma unroll
    for (int mt = 0; mt < 2; ++mt)
        #pragma unroll
        for (int r = 0; r < 4; ++r) {
            float v = bv[mt][r]; int i = bi[mt][r];
            #pragma unroll
            for (int mask = 1; mask <= 8; mask <<= 1) {
                float ov = __shfl_xor(v, mask);
                int oi = __shfl_xor(i, mask);
                if (ov < v || (ov == v && oi < i)) { v = ov; i = oi; }
            }
            bv[mt][r] = v; bi[mt][r] = i;
        }
    if (lm == 0) {
        float lp = 0.f;
        #pragma unroll
        for (int mt = 0; mt < 2; ++mt)
            #pragma unroll
            for (int r = 0; r < 4; ++r) {
                int row_loc = mt * 16 + lq * 4 + r;
                enc[r0 + row_loc] = bi[mt][r];
                atomicAdd(&counts[bi[mt][r]], 1);
                lp += fnbuf[wv * 32 + row_loc] + bv[mt][r];
            }
        atomicAdd(lsum, lp);
    }
}

// ============================ prep2: fc1 weight slices split ============================
// f1s[pos][out][c] = fc1w[out][c*16+pos]
__global__ __launch_bounds__(256) void prep2_kernel(
    const float* __restrict__ fc1w,
    unsigned short* __restrict__ f1h, unsigned short* __restrict__ f1l)
{
    int i = blockIdx.x * 256 + threadIdx.x;   // 2,097,152
    int pos = i >> 17, rem = i & 131071, o = rem >> 8, c = rem & 255;
    float v = fc1w[(size_t)o * 4096 + c * 16 + pos];
    unsigned short h, l; split2(v, &h, &l);
    f1h[i] = h; f1l[i] = l;
}

// ============================ lut: LUT[pos][code][out] = codes . W1-slice ============================
__global__ __launch_bounds__(256, 2) void lut_kernel(
    const unsigned short* __restrict__ codh, const unsigned short* __restrict__ codl,
    const unsigned short* __restrict__ f1h, const unsigned short* __restrict__ f1l,
    float* __restrict__ lut)
{
    const int t = threadIdx.x, b = blockIdx.x;
    const int pos = b >> 5, sub = b & 31, mblk = sub >> 2, nblk = sub & 3;
    const int wv = t >> 6, lane = t & 63, lq = lane >> 4, lm = lane & 15;
    const int mh = wv >> 1, nh = wv & 1;
    f32x4 acc[4][4];
    #pragma unroll
    for (int i = 0; i < 4; ++i)
        #pragma unroll
        for (int j = 0; j < 4; ++j) acc[i][j] = (f32x4){0.f, 0.f, 0.f, 0.f};
    #pragma unroll
    for (int ks = 0; ks < 8; ++ks) {
        bf16x8 ah[4], al[4];
        #pragma unroll
        for (int mt = 0; mt < 4; ++mt) {
            int code = mblk * 128 + mh * 64 + mt * 16 + lm;
            ah[mt] = *(const bf16x8*)(codh + (size_t)code * 256 + ks * 32 + lq * 8);
            al[mt] = *(const bf16x8*)(codl + (size_t)code * 256 + ks * 32 + lq * 8);
        }
        #pragma unroll
        for (int nt = 0; nt < 4; ++nt) {
            int o = nblk * 128 + nh * 64 + nt * 16 + lm;
            bf16x8 bh = *(const bf16x8*)(f1h + ((size_t)pos * 512 + o) * 256 + ks * 32 + lq * 8);
            bf16x8 bl = *(const bf16x8*)(f1l + ((size_t)pos * 512 + o) * 256 + ks * 32 + lq * 8);
            #pragma unroll
            for (int mt = 0; mt < 4; ++mt) {
                acc[mt][nt] = MFMA16(ah[mt], bh, acc[mt][nt]);
                acc[mt][nt] = MFMA16(ah[mt], bl, acc[mt][nt]);
                acc[mt][nt] = MFMA16(al[mt], bh, acc[mt][nt]);
            }
        }
    }
    #pragma unroll
    for (int nt = 0; nt < 4; ++nt) {
        int o = nblk * 128 + nh * 64 + nt * 16 + lm;
        #pragma unroll
        for (int mt = 0; mt < 4; ++mt)
            #pragma unroll
            for (int r = 0; r < 4; ++r) {
                int code = mblk * 128 + mh * 64 + mt * 16 + lq * 4 + r;
                lut[((size_t)pos * 1024 + code) * 512 + o] = acc[mt][nt][r];
            }
    }
}

// ============================ hsum: h = gelu(b1 + sum_pos LUT[pos][enc]) ============================
__device__ inline float gelu_tanh(float x) {
    float x3 = x * x * x;
    float u = 0.7978845608028654f * (x + 0.044715f * x3);
    return 0.5f * x * (1.0f + tanhf(u));
}

__global__ __launch_bounds__(256) void hsum_kernel(
    const int* __restrict__ enc, const float* __restrict__ lut,
    const float* __restrict__ fc1b, float* __restrict__ h)
{
    __shared__ int e[16];
    const int t = threadIdx.x, img = blockIdx.x;
    if (t < 16) e[t] = enc[img * 16 + t];
    __syncthreads();
    for (int rep = 0; rep < 2; ++rep) {
        int o = rep * 256 + t;
        float acc = fc1b[o];
        #pragma unroll
        for (int p = 0; p < 16; ++p)
            acc += lut[((size_t)p * 1024 + e[p]) * 512 + o];
        h[(size_t)img * 512 + o] = gelu_tanh(acc);
    }
}

// ============================ fc2 ============================
__global__ __launch_bounds__(256) void fc2_kernel(
    const float* __restrict__ h, const float* __restrict__ fc2w,
    const float* __restrict__ fc2b, float* __restrict__ out)
{
    __shared__ float ws2[10 * 512];
    const int t = threadIdx.x;
    for (int i = t; i < 5120; i += 256) ws2[i] = fc2w[i];
    __syncthreads();
    const int lane = t & 63, wv = t >> 6;
    const int n = blockIdx.x * 4 + wv;
    float acc[10];
    #pragma unroll
    for (int j = 0; j < 10; ++j) acc[j] = 0.f;
    #pragma unroll
    for (int i = 0; i < 8; ++i) {
        float hv = h[(size_t)n * 512 + lane + 64 * i];
        #pragma unroll
        for (int j = 0; j < 10; ++j) acc[j] += hv * ws2[j * 512 + lane + 64 * i];
    }
    #pragma unroll
    for (int j = 0; j < 10; ++j) {
        float v = acc[j];
        for (int off = 32; off; off >>= 1) v += __shfl_down(v, off);
        if (lane == 0) out[(size_t)n * 10 + j] = v + fc2b[j];
    }
}

// ============================ finalize ============================
__global__ __launch_bounds__(256) void finalize_kernel(
    const int* __restrict__ counts, const float* __restrict__ lsum,
    const int* __restrict__ idxp, float* __restrict__ out)
{
    __shared__ float red[256];
    const int t = threadIdx.x;
    const int Kc = (idxp[0] == 0) ? 512 : 1024;
    float s = 0.f;
    for (int k = t; k < Kc; k += 256) {
        float p = (float)counts[k] * (1.0f / 65536.0f);
        s += p * logf(p + 1e-10f);
    }
    red[t] = s;
    __syncthreads();
    for (int o = 128; o; o >>= 1) {
        if (t < o) red[t] += red[t + o];
        __syncthreads();
    }
    if (t == 0) {
        out[40960] = lsum[0] * (1.25f / 16777216.0f);   // (1+0.25) * mean over 65536*256
        out[40961] = expf(-red[0]);
    }
}

// ============================ launch ============================
extern "C" void kernel_launch(void* const* d_in, const int* in_sizes, int n_in,
                              void* d_out, int out_size, void* d_ws, size_t ws_size,
                              hipStream_t stream)
{
    const float* x     = (const float*)d_in[0];
    const float* w1    = (const float*)d_in[1];
    const float* b1    = (const float*)d_in[2];
    const float* w2    = (const float*)d_in[3];
    const float* b2    = (const float*)d_in[4];
    const float* w3    = (const float*)d_in[5];
    const float* b3    = (const float*)d_in[6];
    const float* code0 = (const float*)d_in[7];
    const float* code1 = (const float*)d_in[8];
    const float* fc1w  = (const float*)d_in[9];
    const float* fc1b  = (const float*)d_in[10];
    const float* fc2w  = (const float*)d_in[11];
    const float* fc2b  = (const float*)d_in[12];
    const int*   idxp  = (const int*)d_in[13];
    float* out = (float*)d_out;
    char* ws = (char*)d_ws;

    unsigned short* w1sh = (unsigned short*)(ws + OFF_W1SH);
    unsigned short* w1sl = (unsigned short*)(ws + OFF_W1SL);
    unsigned short* w2sh = (unsigned short*)(ws + OFF_W2SH);
    unsigned short* w2sl = (unsigned short*)(ws + OFF_W2SL);
    unsigned short* w3sh = (unsigned short*)(ws + OFF_W3SH);
    unsigned short* w3sl = (unsigned short*)(ws + OFF_W3SL);
    unsigned short* codh = (unsigned short*)(ws + OFF_CODH);
    unsigned short* codl = (unsigned short*)(ws + OFF_CODL);
    float* cnorm = (float*)(ws + OFF_CNORM);
    int*   counts= (int*)(ws + OFF_COUNTS);
    float* lsum  = (float*)(ws + OFF_LOSS);
    int*   enc   = (int*)(ws + OFF_ENC);
    unsigned short* y2h = (unsigned short*)(ws + OFF_BIG);
    unsigned short* y2l = (unsigned short*)(ws + OFF_BIG + 67108864);
    unsigned short* fh  = (unsigned short*)(ws + OFF_FLATS);
    unsigned short* fl  = (unsigned short*)(ws + OFF_FLATS + 33554432);
    // post-conv3 aliases (y2 region dead):
    float* lut = (float*)(ws + OFF_BIG);
    float* h   = (float*)(ws + OFF_BIG + 33554432);
    // post-vq aliases (flat region dead):
    unsigned short* f1h = (unsigned short*)(ws + OFF_FLATS);
    unsigned short* f1l = (unsigned short*)(ws + OFF_FLATS + 4194304);

    prep1_kernel<<<2481, 256, 0, stream>>>(w1, w2, w3, code0, code1, idxp,
                                           w1sh, w1sl, w2sh, w2sl, w3sh, w3sl,
                                           codh, codl, cnorm, counts, lsum);
    conv12_kernel<<<8192, 256, 0, stream>>>(x, w1sh, w1sl, b1, w2sh, w2sl, b2, y2h, y2l);
    conv3_kernel<<<512, 256, 0, stream>>>(y2h, y2l, w3sh, w3sl, b3, fh, fl);
    vq_kernel<<<512, 256, 0, stream>>>(fh, fl, codh, codl, cnorm, enc, counts, lsum);
    prep2_kernel<<<8192, 256, 0, stream>>>(fc1w, f1h, f1l);
    lut_kernel<<<512, 256, 0, stream>>>(codh, codl, f1h, f1l, lut);
    hsum_kernel<<<4096, 256, 0, stream>>>(enc, lut, fc1b, h);
    fc2_kernel<<<1024, 256, 0, stream>>>(h, fc2w, fc2b, out);
    finalize_kernel<<<1, 256, 0, stream>>>(counts, lsum, idxp, out);
}